// Round 7
// baseline (323.568 us; speedup 1.0000x reference)
//
#include <hip/hip_runtime.h>
#include <hip/hip_fp16.h>

#define S 1024
#define B 8
#define NH 8
#define DH 32
#define HID 256
#define SCALEF 0.17677669529663687f

typedef __attribute__((ext_vector_type(8))) _Float16 f16x8;
typedef __attribute__((ext_vector_type(4))) _Float16 f16x4;
typedef __attribute__((ext_vector_type(4))) float f32x4;
#define MFMAH(a, b, c) __builtin_amdgcn_mfma_f32_16x16x32_f16(a, b, c, 0, 0, 0)

// ---- LDS layout (halfs), 16128 halfs = 31.5 KB -> 4+ blocks/CU ----
#define OFF_K_H 0
#define OFF_K_L 1280
#define OFF_VT  2560
#define OFF_RL  3840     // single-f16 band, 6 slots x 16 x 40
#define OFF_RH  7680
#define OFF_P   11520    // 4 waves x 16 x 40
#define OFF_SCR 14080    // 64 rows x 32 (f16 scores for sws copy-out)
#define LDS_HF  16128

__device__ __forceinline__ void splitf16_4(const float4 x, _Float16* dh, _Float16* dl) {
  f16x4 h, l;
  h.x = (_Float16)x.x; h.y = (_Float16)x.y; h.z = (_Float16)x.z; h.w = (_Float16)x.w;
  l.x = (_Float16)(x.x - (float)h.x); l.y = (_Float16)(x.y - (float)h.y);
  l.z = (_Float16)(x.z - (float)h.z); l.w = (_Float16)(x.w - (float)h.w);
  *(f16x4*)dh = h; *(f16x4*)dl = l;
}
__device__ __forceinline__ void cvtf16_4(const float4 x, _Float16* d) {
  f16x4 h;
  h.x = (_Float16)x.x; h.y = (_Float16)x.y; h.z = (_Float16)x.z; h.w = (_Float16)x.w;
  *(f16x4*)d = h;
}

// =================== fast path: MFMA kernel ===================
__global__ __launch_bounds__(256)
void relattn_mfma_86028194939537(const float* __restrict__ q, const float* __restrict__ k,
                                 const float* __restrict__ v, const float* __restrict__ r,
                                 const float* __restrict__ bu, const float* __restrict__ bv,
                                 float* __restrict__ out, __half* __restrict__ sws) {
  __shared__ _Float16 sm[LDS_HF];
  const int t = threadIdx.x;
  const int lane = t & 63, w = t >> 6;
  const int quad = lane >> 4, jn = lane & 15;
  const int bid = blockIdx.x;
  const int b = bid & 7, it = (bid >> 3) & 15, n = bid >> 7;
  const int i0 = it << 6, iw0 = i0 + (w << 4);
  const int colq = quad << 3;
  const int i16 = i0 >> 4;

  // ---- A-frags (f16 hi/lo): qu = q+bu (rows iw0+jn), qv = q+bv, qn = q[+1]+bv ----
  f16x8 qu_h, qu_l, qv_h, qv_l, qn_h, qn_l;
  {
    const float* bup = bu + n * DH + colq;
    const float* bvp = bv + n * DH + colq;
    const float* qp = q + (size_t)(iw0 + jn) * 2048 + b * HID + n * DH + colq;
    int r1 = iw0 + 1 + jn; if (r1 > S - 1) r1 = S - 1;
    const float* qp1 = q + (size_t)r1 * 2048 + b * HID + n * DH + colq;
#pragma unroll
    for (int e = 0; e < 8; ++e) {
      float xu = qp[e] + bup[e], xv = qp[e] + bvp[e], xn = qp1[e] + bvp[e];
      _Float16 h;
      h = (_Float16)xu; qu_h[e] = h; qu_l[e] = (_Float16)(xu - (float)h);
      h = (_Float16)xv; qv_h[e] = h; qv_l[e] = (_Float16)(xv - (float)h);
      h = (_Float16)xn; qn_h[e] = h; qn_l[e] = (_Float16)(xn - (float)h);
    }
  }

  f32x4 out0 = {0.f, 0.f, 0.f, 0.f}, out1 = {0.f, 0.f, 0.f, 0.f};
  float ls[4] = {0.f, 0.f, 0.f, 0.f};

  // ---- r ring prologue: 4 tiles per family (single f16) ----
  {
    const int KLb = 60 - i16;
    const int KHb = -i16 - 3;
#pragma unroll
    for (int ss = 0; ss < 2; ++ss) {
      int slot = t + (ss << 8);
      int ti = slot >> 7, row = (slot >> 3) & 15, d4 = (slot & 7) << 2;
      {
        int kL = KLb + ti;
        int tg = (kL << 4) + row; tg = tg < 0 ? 0 : (tg > S - 1 ? S - 1 : tg);
        float4 rv = *(const float4*)(r + (size_t)tg * HID + n * DH + d4);
        int sl = (kL + 66) % 6;
        cvtf16_4(rv, &sm[OFF_RL + (sl * 16 + row) * 40 + d4]);
      }
      {
        int kH = KHb + ti;
        int tg = (kH << 4) - 17 + row; tg = tg < 0 ? 0 : (tg > S - 1 ? S - 1 : tg);
        float4 rv = *(const float4*)(r + (size_t)tg * HID + n * DH + d4);
        int sl = (kH + 66) % 6;
        cvtf16_4(rv, &sm[OFF_RH + (sl * 16 + row) * 40 + d4]);
      }
    }
  }

  for (int jt = 0; jt < 32; ++jt) {
    const int j0 = jt << 5;
    // ---- stage K (h/l) and V^T (f16) chunk (32 j x 32 d) ----
    {
      int j = t >> 3, d4 = (t & 7) << 2;
      const size_t g = (size_t)(j0 + j) * 2048 + b * HID + n * DH + d4;
      float4 kx = *(const float4*)(k + g);
      float4 vx = *(const float4*)(v + g);
      splitf16_4(kx, &sm[OFF_K_H + j * 40 + d4], &sm[OFF_K_L + j * 40 + d4]);
      sm[OFF_VT + (d4 + 0) * 40 + j] = (_Float16)vx.x;
      sm[OFF_VT + (d4 + 1) * 40 + j] = (_Float16)vx.y;
      sm[OFF_VT + (d4 + 2) * 40 + j] = (_Float16)vx.z;
      sm[OFF_VT + (d4 + 3) * 40 + j] = (_Float16)vx.w;
    }
    // ---- stage 2 new r tiles per family ----
    {
      int ti = t >> 7, row = (t >> 3) & 15, d4 = (t & 7) << 2;
      {
        int kL = 64 - i16 + 2 * jt + ti;
        int tg = (kL << 4) + row; tg = tg < 0 ? 0 : (tg > S - 1 ? S - 1 : tg);
        float4 rv = *(const float4*)(r + (size_t)tg * HID + n * DH + d4);
        int sl = (kL + 66) % 6;
        cvtf16_4(rv, &sm[OFF_RL + (sl * 16 + row) * 40 + d4]);
      }
      {
        int kH = 1 - i16 + 2 * jt + ti;
        int tg = (kH << 4) - 17 + row; tg = tg < 0 ? 0 : (tg > S - 1 ? S - 1 : tg);
        float4 rv = *(const float4*)(r + (size_t)tg * HID + n * DH + d4);
        int sl = (kH + 66) % 6;
        cvtf16_4(rv, &sm[OFF_RH + (sl * 16 + row) * 40 + d4]);
      }
    }
    __syncthreads();

    const bool lowA = (j0 <= iw0 + 15);
    const bool highA = (j0 + 29 >= iw0);

    // ---- AC = (q+bu) . k^T : 2 N-tiles, 3-term f16 ----
    f32x4 ac0 = {0.f, 0.f, 0.f, 0.f}, ac1 = {0.f, 0.f, 0.f, 0.f};
    {
      f16x8 b0h = *(const f16x8*)&sm[OFF_K_H + jn * 40 + colq];
      f16x8 b0l = *(const f16x8*)&sm[OFF_K_L + jn * 40 + colq];
      f16x8 b1h = *(const f16x8*)&sm[OFF_K_H + (16 + jn) * 40 + colq];
      f16x8 b1l = *(const f16x8*)&sm[OFF_K_L + (16 + jn) * 40 + colq];
      ac0 = MFMAH(qu_h, b0h, ac0); ac0 = MFMAH(qu_h, b0l, ac0); ac0 = MFMAH(qu_l, b0h, ac0);
      ac1 = MFMAH(qu_h, b1h, ac1); ac1 = MFMAH(qu_h, b1l, ac1); ac1 = MFMAH(qu_l, b1h, ac1);
    }

    // ---- Z bands (single-f16 r: 2 MFMA per tile) ----
    f32x4 zl0 = {0.f,0.f,0.f,0.f}, zl1 = {0.f,0.f,0.f,0.f}, zl2 = {0.f,0.f,0.f,0.f};
    f32x4 zh0 = {0.f,0.f,0.f,0.f}, zh1 = {0.f,0.f,0.f,0.f}, zh2 = {0.f,0.f,0.f,0.f};
    if (lowA) {
#pragma unroll
      for (int z = 0; z < 3; ++z) {
        int kL = 63 - i16 - w + 2 * jt + z;
        int sl = (kL + 66) % 6;
        f16x8 rr = *(const f16x8*)&sm[OFF_RL + (sl * 16 + jn) * 40 + colq];
        f32x4 acc = {0.f, 0.f, 0.f, 0.f};
        acc = MFMAH(qv_h, rr, acc); acc = MFMAH(qv_l, rr, acc);
        if (z == 0) zl0 = acc; else if (z == 1) zl1 = acc; else zl2 = acc;
      }
    }
    if (highA) {
#pragma unroll
      for (int z = 0; z < 3; ++z) {
        int kH = 2 * jt - i16 - w + z;
        int sl = (kH + 66) % 6;
        f16x8 rr = *(const f16x8*)&sm[OFF_RH + (sl * 16 + jn) * 40 + colq];
        f32x4 acc = {0.f, 0.f, 0.f, 0.f};
        acc = MFMAH(qn_h, rr, acc); acc = MFMAH(qn_l, rr, acc);
        if (z == 0) zh0 = acc; else if (z == 1) zh1 = acc; else zh2 = acc;
      }
    }

    // ---- gather + score + P ----
#pragma unroll
    for (int g = 0; g < 4; ++g) {
      const int qr = (quad << 2) + g;
      const int c0 = 15 - qr + jn;
      const int src = (lane & 48) | (c0 & 15);
      const bool zs = (c0 < 16);
      float lo0 = 0.f, lo1 = 0.f, hv0 = 0.f, hv1 = 0.f;
      if (lowA) {
        float a0 = __shfl(zl0[g], src, 64);
        float a1 = __shfl(zl1[g], src, 64);
        float a2 = __shfl(zl2[g], src, 64);
        lo0 = zs ? a0 : a1; lo1 = zs ? a1 : a2;
      }
      if (highA) {
        float a0 = __shfl(zh0[g], src, 64);
        float a1 = __shfl(zh1[g], src, 64);
        float a2 = __shfl(zh2[g], src, 64);
        hv0 = zs ? a0 : a1; hv1 = zs ? a1 : a2;
      }
      const int dj0 = j0 + jn - iw0 - qr;
#pragma unroll
      for (int f = 0; f < 2; ++f) {
        const int dj = dj0 + (f << 4);
        const float bd = (dj <= 0) ? (f ? lo1 : lo0) : ((dj == 1) ? 0.f : (f ? hv1 : hv0));
        const float acv = f ? ac1[g] : ac0[g];
        float sr = (acv + bd) * SCALEF;
        sr = fminf(fmaxf(sr, -15.f), 15.f);
        const float e2 = __expf(2.f * sr);
        const float scv = 10.f - 20.f * __builtin_amdgcn_rcpf(e2 + 1.f);
        sm[OFF_SCR + ((w << 4) + qr) * 32 + (f << 4) + jn] = (_Float16)scv;
        const float pw = __expf(scv);
        const _Float16 ph = (_Float16)pw;
        ls[g] += (float)ph;
        sm[OFF_P + w * 640 + qr * 40 + (f << 4) + jn] = ph;
      }
    }

    // ---- PV: out += P(f16) . V^T(f16) ----
    {
      f16x8 pa = *(const f16x8*)&sm[OFF_P + w * 640 + jn * 40 + colq];
      f16x8 v0 = *(const f16x8*)&sm[OFF_VT + jn * 40 + colq];
      f16x8 v1 = *(const f16x8*)&sm[OFF_VT + (16 + jn) * 40 + colq];
      out0 = MFMAH(pa, v0, out0);
      out1 = MFMAH(pa, v1, out1);
    }
    __syncthreads();
    // ---- copy scores LDS -> sws as wide stores (after barrier: all waves' scr visible) ----
    {
      int r64 = t >> 2, c8 = (t & 3) << 3;
      f16x8 sv = *(const f16x8*)&sm[OFF_SCR + r64 * 32 + c8];
      *(f16x8*)(sws + (((size_t)(i0 + r64) * 8 + b) * 8 + n) * 1024 + j0 + c8) = sv;
    }
  }

  // ---- epilogue: rowsum reduce + normalized out write ----
#pragma unroll
  for (int g = 0; g < 4; ++g) {
    float s = ls[g];
    s += __shfl_xor(s, 1, 64); s += __shfl_xor(s, 2, 64);
    s += __shfl_xor(s, 4, 64); s += __shfl_xor(s, 8, 64);
    const float inv = 1.0f / s;
    const int qr = (quad << 2) + g;
    float* op = out + (size_t)(iw0 + qr) * 2048 + b * HID + n * DH;
    op[jn] = out0[g] * inv;
    op[16 + jn] = out1[g] * inv;
  }
}

// =================== fast path: probs kernel v3 (LDS-staged mask, all coalesced) ===================
__global__ __launch_bounds__(256)
void relattn_probs_86028194939537(const __half* __restrict__ sws, const int* __restrict__ mask,
                                  float* __restrict__ probs) {
  __shared__ _Float16 ebuf[8][1032];     // 16.1 KB
  __shared__ unsigned char mb[8192];     // 8 KB
  __shared__ float bsum[8][4];
  __shared__ float binv[8];
  const int t = threadIdx.x;
  const int i = blockIdx.x;
  const int wv = t >> 6;
  const int j4 = t << 2;

  // stage mask coalesced: 8192 ints -> 8192 bytes
  {
    const int4* m4 = (const int4*)(mask + (size_t)i * 8192);
#pragma unroll
    for (int u = 0; u < 8; ++u) {
      int idx = t + (u << 8);
      int4 mv = m4[idx];
      uchar4 mbv;
      mbv.x = (unsigned char)(mv.x != 0); mbv.y = (unsigned char)(mv.y != 0);
      mbv.z = (unsigned char)(mv.z != 0); mbv.w = (unsigned char)(mv.w != 0);
      *(uchar4*)&mb[idx << 2] = mbv;
    }
  }
  __syncthreads();

#pragma unroll
  for (int b = 0; b < 8; ++b) {
    float a0 = 0.f, a1 = 0.f, a2 = 0.f, a3 = 0.f;
#pragma unroll
    for (int n = 0; n < 8; ++n) {
      const __half2* p2 = (const __half2*)(sws + (((size_t)i * 8 + b) * 8 + n) * 1024 + j4);
      float2 x = __half22float2(p2[0]), y = __half22float2(p2[1]);
      a0 += x.x; a1 += x.y; a2 += y.x; a3 += y.y;
    }
    float e0 = mb[(j4 + 0) * 8 + b] ? 0.f : __expf(a0 * 0.125f);
    float e1 = mb[(j4 + 1) * 8 + b] ? 0.f : __expf(a1 * 0.125f);
    float e2 = mb[(j4 + 2) * 8 + b] ? 0.f : __expf(a2 * 0.125f);
    float e3 = mb[(j4 + 3) * 8 + b] ? 0.f : __expf(a3 * 0.125f);
    f16x4 ev;
    ev.x = (_Float16)e0; ev.y = (_Float16)e1; ev.z = (_Float16)e2; ev.w = (_Float16)e3;
    *(f16x4*)&ebuf[b][j4] = ev;
    float s = ((float)ev.x + (float)ev.y) + ((float)ev.z + (float)ev.w);
#pragma unroll
    for (int off = 32; off > 0; off >>= 1) s += __shfl_xor(s, off, 64);
    if ((t & 63) == 0) bsum[b][wv] = s;
  }
  __syncthreads();
  if (t < 8) binv[t] = 1.0f / (bsum[t][0] + bsum[t][1] + bsum[t][2] + bsum[t][3]);
  __syncthreads();
#pragma unroll
  for (int u = 0; u < 8; ++u) {
    int f0 = j4 + (u << 10);
    float4 o;
    o.x = (float)ebuf[(f0 + 0) & 7][(f0 + 0) >> 3] * binv[(f0 + 0) & 7];
    o.y = (float)ebuf[(f0 + 1) & 7][(f0 + 1) >> 3] * binv[(f0 + 1) & 7];
    o.z = (float)ebuf[(f0 + 2) & 7][(f0 + 2) >> 3] * binv[(f0 + 2) & 7];
    o.w = (float)ebuf[(f0 + 3) & 7][(f0 + 3) >> 3] * binv[(f0 + 3) & 7];
    *(float4*)(probs + (size_t)i * 8192 + f0) = o;
  }
}

// =================== fallback (R4, proven) ===================
#define TI 8
#define TJ 8
#define NTILE (S / TJ)
#define KSTR 288
#define KOFF 0
#define VOFF (TJ * KSTR)
#define BAND (2 * TJ * KSTR)
#define PROWS (TI + TJ - 1)
#define BSTR 292
#define BVR (BAND + PROWS * BSTR)
#define BUKo (BVR + PROWS * 8)
#define LDS_FL (BUKo + 64)

__global__ __launch_bounds__(256, 2)
void relattn_main_fb(const float* __restrict__ q, const float* __restrict__ k,
                     const float* __restrict__ v, const float* __restrict__ r,
                     const float* __restrict__ bias_u, const float* __restrict__ bias_v,
                     const int* __restrict__ mask, float* __restrict__ out,
                     float* __restrict__ probs_raw, float* __restrict__ ws_logits, int use_ws) {
  __shared__ float smf[LDS_FL];
  const int t = threadIdx.x;
  const int n = t & 7;
  const int il = (t >> 3) & 7;
  const int jp = t >> 6;
  const int bid = blockIdx.x;
  const int b = bid & 7;
  const int i0 = (bid >> 3) * TI;
  const int i = i0 + il;
  float qq[DH], qn[DH];
  {
    const float4* qr = (const float4*)(q + (i * B + b) * HID + n * DH);
#pragma unroll
    for (int dd = 0; dd < 8; ++dd) {
      float4 a = qr[dd];
      qq[4*dd+0] = a.x; qq[4*dd+1] = a.y; qq[4*dd+2] = a.z; qq[4*dd+3] = a.w;
    }
    if (i + 1 < S) {
      const float4* q2 = (const float4*)(q + ((i + 1) * B + b) * HID + n * DH);
#pragma unroll
      for (int dd = 0; dd < 8; ++dd) {
        float4 a = q2[dd];
        qn[4*dd+0] = a.x; qn[4*dd+1] = a.y; qn[4*dd+2] = a.z; qn[4*dd+3] = a.w;
      }
    } else {
#pragma unroll
      for (int d = 0; d < DH; ++d) qn[d] = 0.f;
    }
  }
  float oacc[DH];
#pragma unroll
  for (int d = 0; d < DH; ++d) oacc[d] = 0.f;
  float lsum = 0.f;
  for (int jt = 0; jt < NTILE; ++jt) {
    const int j0 = jt * TJ;
    const int Pstar = i0 + (TI - 1) - j0;
    const int lowBase = S - TI + j0 - i0;
    const int upBase = j0 - i0 - (TI + 1);
    __syncthreads();
    {
      int u = t;
      int row = u >> 6, c = u & 63;
      int gofs = ((j0 + row) * B + b) * HID + c * 4;
      int lofs = row * KSTR + (c >> 3) * 36 + (c & 7) * 4;
      *(float4*)(smf + KOFF + lofs) = *(const float4*)(k + gofs);
      *(float4*)(smf + VOFF + lofs) = *(const float4*)(v + gofs);
      u = t + 256; row = u >> 6; c = u & 63;
      gofs = ((j0 + row) * B + b) * HID + c * 4;
      lofs = row * KSTR + (c >> 3) * 36 + (c & 7) * 4;
      *(float4*)(smf + KOFF + lofs) = *(const float4*)(k + gofs);
      *(float4*)(smf + VOFF + lofs) = *(const float4*)(v + gofs);
    }
    for (int u = t; u < PROWS * 64; u += 256) {
      int prow = u >> 6, c = u & 63;
      int trow = (prow <= Pstar) ? (lowBase + prow) : (upBase + prow);
      float4 val = make_float4(0.f, 0.f, 0.f, 0.f);
      if ((unsigned)trow < (unsigned)S) val = *(const float4*)(r + trow * HID + c * 4);
      *(float4*)(smf + BAND + prow * BSTR + (c >> 3) * 36 + (c & 7) * 4) = val;
    }
    if (t < 64 + PROWS * 8) {
      const float4 *bb, *src;
      int slot;
      bool zero = false;
      if (t < 64) {
        int jl = t >> 3, nn = t & 7;
        bb = (const float4*)(bias_u + nn * DH);
        src = (const float4*)(k + ((j0 + jl) * B + b) * HID + nn * DH);
        slot = BUKo + jl * 8 + nn;
      } else {
        int u2 = t - 64;
        int prow = u2 >> 3, nn = u2 & 7;
        int trow = (prow <= Pstar) ? (lowBase + prow) : (upBase + prow);
        bb = (const float4*)(bias_v + nn * DH);
        if ((unsigned)trow < (unsigned)S) src = (const float4*)(r + trow * HID + nn * DH);
        else { src = bb; zero = true; }
        slot = BVR + prow * 8 + nn;
      }
      float a0 = 0.f, a1 = 0.f, a2 = 0.f, a3 = 0.f;
#pragma unroll
      for (int dd = 0; dd < 8; ++dd) {
        float4 x = bb[dd], y = src[dd];
        a0 = fmaf(x.x, y.x, a0); a1 = fmaf(x.y, y.y, a1);
        a2 = fmaf(x.z, y.z, a2); a3 = fmaf(x.w, y.w, a3);
      }
      smf[slot] = zero ? 0.f : ((a0 + a1) + (a2 + a3));
    }
    __syncthreads();
#pragma unroll
    for (int jj = 0; jj < 2; ++jj) {
      const int jl = jp * 2 + jj;
      const int jg = j0 + jl;
      const int p = jl + (TI - 1) - il;
      float a0 = 0.f, a1 = 0.f, a2 = 0.f, a3 = 0.f;
      const float4* kr = (const float4*)(smf + KOFF + jl * KSTR + n * 36);
#pragma unroll
      for (int dd = 0; dd < 8; ++dd) {
        float4 kv = kr[dd];
        a0 = fmaf(qq[4*dd+0], kv.x, a0); a1 = fmaf(qq[4*dd+1], kv.y, a1);
        a2 = fmaf(qq[4*dd+2], kv.z, a2); a3 = fmaf(qq[4*dd+3], kv.w, a3);
      }
      float ac = (a0 + a1) + (a2 + a3) + smf[BUKo + jl * 8 + n];
      float b0 = 0.f, b1 = 0.f, b2 = 0.f, b3 = 0.f;
      const float4* br = (const float4*)(smf + BAND + p * BSTR + n * 36);
      if (jg <= i) {
#pragma unroll
        for (int dd = 0; dd < 8; ++dd) {
          float4 bv4 = br[dd];
          b0 = fmaf(qq[4*dd+0], bv4.x, b0); b1 = fmaf(qq[4*dd+1], bv4.y, b1);
          b2 = fmaf(qq[4*dd+2], bv4.z, b2); b3 = fmaf(qq[4*dd+3], bv4.w, b3);
        }
      } else {
#pragma unroll
        for (int dd = 0; dd < 8; ++dd) {
          float4 bv4 = br[dd];
          b0 = fmaf(qn[4*dd+0], bv4.x, b0); b1 = fmaf(qn[4*dd+1], bv4.y, b1);
          b2 = fmaf(qn[4*dd+2], bv4.z, b2); b3 = fmaf(qn[4*dd+3], bv4.w, b3);
        }
      }
      float bd = (b0 + b1) + (b2 + b3) + smf[BVR + p * 8 + n];
      float sr = (ac + bd) * SCALEF;
      sr = fminf(fmaxf(sr, -15.f), 15.f);
      float e2 = __expf(2.f * sr);
      float scv = 10.f * (e2 - 1.f) / (e2 + 1.f);
      float ssum = scv;
      ssum += __shfl_xor(ssum, 1, 64);
      ssum += __shfl_xor(ssum, 2, 64);
      ssum += __shfl_xor(ssum, 4, 64);
      if (n == 0) {
        float logit = ssum * 0.125f;
        if (use_ws) {
          ws_logits[(i * B + b) * S + jg] = logit;
        } else {
          int gofs = (i * S + jg) * B + b;
          probs_raw[gofs] = (mask[gofs] != 0) ? -1e30f : logit;
        }
      }
      float pw = __expf(scv);
      lsum += pw;
      const float4* vr = (const float4*)(smf + VOFF + jl * KSTR + n * 36);
#pragma unroll
      for (int dd = 0; dd < 8; ++dd) {
        float4 vv = vr[dd];
        oacc[4*dd+0] = fmaf(pw, vv.x, oacc[4*dd+0]);
        oacc[4*dd+1] = fmaf(pw, vv.y, oacc[4*dd+1]);
        oacc[4*dd+2] = fmaf(pw, vv.z, oacc[4*dd+2]);
        oacc[4*dd+3] = fmaf(pw, vv.w, oacc[4*dd+3]);
      }
    }
  }
  __syncthreads();
  if (jp >= 2) {
    float* red = smf + (t - 128) * 33;
#pragma unroll
    for (int d = 0; d < DH; ++d) red[d] = oacc[d];
    red[DH] = lsum;
  }
  __syncthreads();
  if (jp < 2) {
    const float* red = smf + t * 33;
#pragma unroll
    for (int d = 0; d < DH; ++d) oacc[d] += red[d];
    lsum += red[DH];
  }
  __syncthreads();
  if (jp == 1) {
    float* red = smf + (t - 64) * 33;
#pragma unroll
    for (int d = 0; d < DH; ++d) red[d] = oacc[d];
    red[DH] = lsum;
  }
  __syncthreads();
  if (jp == 0) {
    const float* red = smf + t * 33;
#pragma unroll
    for (int d = 0; d < DH; ++d) oacc[d] += red[d];
    lsum += red[DH];
    float inv = 1.f / lsum;
    float4* orow = (float4*)(out + (i * B + b) * HID + n * DH);
#pragma unroll
    for (int dd = 0; dd < 8; ++dd) {
      float4 o4;
      o4.x = oacc[4*dd+0] * inv; o4.y = oacc[4*dd+1] * inv;
      o4.z = oacc[4*dd+2] * inv; o4.w = oacc[4*dd+3] * inv;
      orow[dd] = o4;
    }
  }
}

__global__ __launch_bounds__(256)
void relattn_norm_fb(float* __restrict__ probs, const float* __restrict__ ws_logits,
                     const int* __restrict__ mask, int use_ws) {
  const int t = threadIdx.x;
  const int bid = blockIdx.x;
  const int b = bid & 7;
  const int i = bid >> 3;
  float vals[4];
  float s = 0.f;
#pragma unroll
  for (int kk = 0; kk < 4; ++kk) {
    int j = t + 256 * kk;
    float lg;
    if (use_ws) {
      lg = ws_logits[(i * B + b) * S + j];
      if (mask[(i * S + j) * B + b] != 0) lg = -1e30f;
    } else {
      lg = probs[(i * S + j) * B + b];
    }
    vals[kk] = __expf(lg);
    s += vals[kk];
  }
#pragma unroll
  for (int off = 32; off > 0; off >>= 1) s += __shfl_down(s, off, 64);
  __shared__ float wsum[4];
  __shared__ float tot;
  if ((t & 63) == 0) wsum[t >> 6] = s;
  __syncthreads();
  if (t == 0) tot = wsum[0] + wsum[1] + wsum[2] + wsum[3];
  __syncthreads();
  float inv = 1.f / tot;
#pragma unroll
  for (int kk = 0; kk < 4; ++kk) {
    int j = t + 256 * kk;
    probs[(i * S + j) * B + b] = vals[kk] * inv;
  }
}

extern "C" void kernel_launch(void* const* d_in, const int* in_sizes, int n_in,
                              void* d_out, int out_size, void* d_ws, size_t ws_size,
                              hipStream_t stream) {
  const float* q  = (const float*)d_in[0];
  const float* k  = (const float*)d_in[1];
  const float* v  = (const float*)d_in[2];
  const float* r  = (const float*)d_in[3];
  const float* bu = (const float*)d_in[4];
  const float* bv = (const float*)d_in[5];
  const int* mask = (const int*)d_in[6];
  float* out = (float*)d_out;
  float* probs = out + S * B * HID;

  const size_t WS_NEED = (size_t)S * S * B * NH * sizeof(__half);  // 128 MiB
  if (ws_size >= WS_NEED) {
    __half* sws = (__half*)d_ws;
    relattn_mfma_86028194939537<<<dim3(1024), dim3(256), 0, stream>>>(
        q, k, v, r, bu, bv, out, sws);
    relattn_probs_86028194939537<<<dim3(1024), dim3(256), 0, stream>>>(sws, mask, probs);
  } else {
    float* wsl = (float*)d_ws;
    const int use_ws = (ws_size >= (size_t)S * S * B * sizeof(float)) ? 1 : 0;
    relattn_main_fb<<<dim3((S / TI) * B), dim3(256), 0, stream>>>(
        q, k, v, r, bu, bv, mask, out, probs, wsl, use_ws);
    relattn_norm_fb<<<dim3(S * B), dim3(256), 0, stream>>>(probs, wsl, mask, use_ws);
  }
}

// Round 8
// 283.696 us; speedup vs baseline: 1.1405x; 1.1405x over previous
//
#include <hip/hip_runtime.h>
#include <hip/hip_fp16.h>

#define S 1024
#define B 8
#define NH 8
#define DH 32
#define HID 256
#define SCALEF 0.17677669529663687f

typedef __attribute__((ext_vector_type(8))) _Float16 f16x8;
typedef __attribute__((ext_vector_type(4))) _Float16 f16x4;
typedef __attribute__((ext_vector_type(4))) float f32x4;
#define MFMAH(a, b, c) __builtin_amdgcn_mfma_f32_16x16x32_f16(a, b, c, 0, 0, 0)

// ---- LDS layout (halfs), 20480 halfs = 40 KB ----
#define OFF_K_H 0        // 2 buf x 32 x 40
#define OFF_K_L 2560
#define OFF_VT  5120     // 2 buf x 32(d) x 40
#define OFF_RL  7680     // ring 8 slots x 16 x 40
#define OFF_RH  12800
#define OFF_P   17920    // 4 waves x 16 x 40
#define LDS_HF  20480

__device__ __forceinline__ void splitf16_4(const float4 x, _Float16* dh, _Float16* dl) {
  f16x4 h, l;
  h.x = (_Float16)x.x; h.y = (_Float16)x.y; h.z = (_Float16)x.z; h.w = (_Float16)x.w;
  l.x = (_Float16)(x.x - (float)h.x); l.y = (_Float16)(x.y - (float)h.y);
  l.z = (_Float16)(x.z - (float)h.z); l.w = (_Float16)(x.w - (float)h.w);
  *(f16x4*)dh = h; *(f16x4*)dl = l;
}
__device__ __forceinline__ void cvtf16_4(const float4 x, _Float16* d) {
  f16x4 h;
  h.x = (_Float16)x.x; h.y = (_Float16)x.y; h.z = (_Float16)x.z; h.w = (_Float16)x.w;
  *(f16x4*)d = h;
}

// =================== fast path: MFMA kernel ===================
__global__ __launch_bounds__(256)
void relattn_mfma_86028194939537(const float* __restrict__ q, const float* __restrict__ k,
                                 const float* __restrict__ v, const float* __restrict__ r,
                                 const float* __restrict__ bu, const float* __restrict__ bv,
                                 float* __restrict__ out, __half* __restrict__ sws) {
  __shared__ _Float16 sm[LDS_HF];
  const int t = threadIdx.x;
  const int lane = t & 63, w = t >> 6;
  const int quad = lane >> 4, jn = lane & 15;
  const int bid = blockIdx.x;
  const int b = bid & 7, it = (bid >> 3) & 15, n = bid >> 7;
  const int i0 = it << 6, iw0 = i0 + (w << 4);
  const int colq = quad << 3;
  const int i16 = i0 >> 4;

  // ---- A-frags (f16 hi/lo): qu = q+bu (rows iw0+jn), qv = q+bv, qn = q[+1]+bv ----
  f16x8 qu_h, qu_l, qv_h, qv_l, qn_h, qn_l;
  {
    const float* bup = bu + n * DH + colq;
    const float* bvp = bv + n * DH + colq;
    const float* qp = q + (size_t)(iw0 + jn) * 2048 + b * HID + n * DH + colq;
    int r1 = iw0 + 1 + jn; if (r1 > S - 1) r1 = S - 1;
    const float* qp1 = q + (size_t)r1 * 2048 + b * HID + n * DH + colq;
#pragma unroll
    for (int e = 0; e < 8; ++e) {
      float xu = qp[e] + bup[e], xv = qp[e] + bvp[e], xn = qp1[e] + bvp[e];
      _Float16 h;
      h = (_Float16)xu; qu_h[e] = h; qu_l[e] = (_Float16)(xu - (float)h);
      h = (_Float16)xv; qv_h[e] = h; qv_l[e] = (_Float16)(xv - (float)h);
      h = (_Float16)xn; qn_h[e] = h; qn_l[e] = (_Float16)(xn - (float)h);
    }
  }

  // sws row base pointers (hoisted)
  __half* swsr[4];
#pragma unroll
  for (int g = 0; g < 4; ++g) {
    const int qr = (quad << 2) + g;
    swsr[g] = sws + (((size_t)(iw0 + qr) * 8 + b) * 8 + n) * 1024 + jn;
  }

  f32x4 out0 = {0.f, 0.f, 0.f, 0.f}, out1 = {0.f, 0.f, 0.f, 0.f};
  float ls[4] = {0.f, 0.f, 0.f, 0.f};

  // ---- prologue: K/V buf0 (jt=0) + 6 r tiles per family ----
  {
    int j = t >> 3, d4 = (t & 7) << 2;
    const size_t g = (size_t)j * 2048 + b * HID + n * DH + d4;
    float4 kx = *(const float4*)(k + g);
    float4 vx = *(const float4*)(v + g);
    splitf16_4(kx, &sm[OFF_K_H + j * 40 + d4], &sm[OFF_K_L + j * 40 + d4]);
    sm[OFF_VT + (d4 + 0) * 40 + j] = (_Float16)vx.x;
    sm[OFF_VT + (d4 + 1) * 40 + j] = (_Float16)vx.y;
    sm[OFF_VT + (d4 + 2) * 40 + j] = (_Float16)vx.z;
    sm[OFF_VT + (d4 + 3) * 40 + j] = (_Float16)vx.w;
  }
#pragma unroll
  for (int p = 0; p < 3; ++p) {
    int ti = 2 * p + (t >> 7), row = (t >> 3) & 15, d4 = (t & 7) << 2;
    {
      int kL = 60 - i16 + ti;
      int tg = (kL << 4) + row; tg = tg < 0 ? 0 : (tg > S - 1 ? S - 1 : tg);
      float4 rv = *(const float4*)(r + (size_t)tg * HID + n * DH + d4);
      int sl = (kL + 72) & 7;
      cvtf16_4(rv, &sm[OFF_RL + (sl * 16 + row) * 40 + d4]);
    }
    {
      int kH = -i16 - 3 + ti;
      int tg = (kH << 4) - 17 + row; tg = tg < 0 ? 0 : (tg > S - 1 ? S - 1 : tg);
      float4 rv = *(const float4*)(r + (size_t)tg * HID + n * DH + d4);
      int sl = (kH + 72) & 7;
      cvtf16_4(rv, &sm[OFF_RH + (sl * 16 + row) * 40 + d4]);
    }
  }

  for (int jt = 0; jt < 32; ++jt) {
    const int j0 = jt << 5;
    __syncthreads();   // the ONLY barrier per jt

    // ---- stage next K/V (buf^1) and 2 r tiles per family (slots ahead) ----
    if (jt < 31) {
      int j = t >> 3, d4 = (t & 7) << 2;
      const int nbuf = ((jt + 1) & 1) * 1280;
      const size_t g = (size_t)(j0 + 32 + j) * 2048 + b * HID + n * DH + d4;
      float4 kx = *(const float4*)(k + g);
      float4 vx = *(const float4*)(v + g);
      splitf16_4(kx, &sm[OFF_K_H + nbuf + j * 40 + d4], &sm[OFF_K_L + nbuf + j * 40 + d4]);
      sm[OFF_VT + nbuf + (d4 + 0) * 40 + j] = (_Float16)vx.x;
      sm[OFF_VT + nbuf + (d4 + 1) * 40 + j] = (_Float16)vx.y;
      sm[OFF_VT + nbuf + (d4 + 2) * 40 + j] = (_Float16)vx.z;
      sm[OFF_VT + nbuf + (d4 + 3) * 40 + j] = (_Float16)vx.w;
    }
    {
      int ti = t >> 7, row = (t >> 3) & 15, d4 = (t & 7) << 2;
      {
        int kL = 66 + 2 * jt - i16 + ti;
        int tg = (kL << 4) + row; tg = tg < 0 ? 0 : (tg > S - 1 ? S - 1 : tg);
        float4 rv = *(const float4*)(r + (size_t)tg * HID + n * DH + d4);
        int sl = (kL + 72) & 7;
        cvtf16_4(rv, &sm[OFF_RL + (sl * 16 + row) * 40 + d4]);
      }
      {
        int kH = 2 * jt - i16 + 3 + ti;
        int tg = (kH << 4) - 17 + row; tg = tg < 0 ? 0 : (tg > S - 1 ? S - 1 : tg);
        float4 rv = *(const float4*)(r + (size_t)tg * HID + n * DH + d4);
        int sl = (kH + 72) & 7;
        cvtf16_4(rv, &sm[OFF_RH + (sl * 16 + row) * 40 + d4]);
      }
    }

    const int buf = (jt & 1) * 1280;
    const bool lowA = (j0 <= iw0 + 15);
    const bool highA = (j0 + 29 >= iw0);

    // ---- AC = (q+bu) . k^T : 2 N-tiles, 3-term f16 ----
    f32x4 ac0 = {0.f, 0.f, 0.f, 0.f}, ac1 = {0.f, 0.f, 0.f, 0.f};
    {
      f16x8 b0h = *(const f16x8*)&sm[OFF_K_H + buf + jn * 40 + colq];
      f16x8 b0l = *(const f16x8*)&sm[OFF_K_L + buf + jn * 40 + colq];
      f16x8 b1h = *(const f16x8*)&sm[OFF_K_H + buf + (16 + jn) * 40 + colq];
      f16x8 b1l = *(const f16x8*)&sm[OFF_K_L + buf + (16 + jn) * 40 + colq];
      ac0 = MFMAH(qu_h, b0h, ac0); ac0 = MFMAH(qu_h, b0l, ac0); ac0 = MFMAH(qu_l, b0h, ac0);
      ac1 = MFMAH(qu_h, b1h, ac1); ac1 = MFMAH(qu_h, b1l, ac1); ac1 = MFMAH(qu_l, b1h, ac1);
    }

    // ---- Z bands (single-f16 r: 2 MFMA per tile) ----
    f32x4 zl0 = {0.f,0.f,0.f,0.f}, zl1 = {0.f,0.f,0.f,0.f}, zl2 = {0.f,0.f,0.f,0.f};
    f32x4 zh0 = {0.f,0.f,0.f,0.f}, zh1 = {0.f,0.f,0.f,0.f}, zh2 = {0.f,0.f,0.f,0.f};
    if (lowA) {
#pragma unroll
      for (int z = 0; z < 3; ++z) {
        int kL = 63 - i16 - w + 2 * jt + z;
        int sl = (kL + 72) & 7;
        f16x8 rr = *(const f16x8*)&sm[OFF_RL + (sl * 16 + jn) * 40 + colq];
        f32x4 acc = {0.f, 0.f, 0.f, 0.f};
        acc = MFMAH(qv_h, rr, acc); acc = MFMAH(qv_l, rr, acc);
        if (z == 0) zl0 = acc; else if (z == 1) zl1 = acc; else zl2 = acc;
      }
    }
    if (highA) {
#pragma unroll
      for (int z = 0; z < 3; ++z) {
        int kH = 2 * jt - i16 - w + z;
        int sl = (kH + 72) & 7;
        f16x8 rr = *(const f16x8*)&sm[OFF_RH + (sl * 16 + jn) * 40 + colq];
        f32x4 acc = {0.f, 0.f, 0.f, 0.f};
        acc = MFMAH(qn_h, rr, acc); acc = MFMAH(qn_l, rr, acc);
        if (z == 0) zh0 = acc; else if (z == 1) zh1 = acc; else zh2 = acc;
      }
    }

    // ---- gather + score + P ----
#pragma unroll
    for (int g = 0; g < 4; ++g) {
      const int qr = (quad << 2) + g;
      const int c0 = 15 - qr + jn;
      const int src = (lane & 48) | (c0 & 15);
      const bool zs = (c0 < 16);
      float lo0 = 0.f, lo1 = 0.f, hv0 = 0.f, hv1 = 0.f;
      if (lowA) {
        float a0 = __shfl(zl0[g], src, 64);
        float a1 = __shfl(zl1[g], src, 64);
        float a2 = __shfl(zl2[g], src, 64);
        lo0 = zs ? a0 : a1; lo1 = zs ? a1 : a2;
      }
      if (highA) {
        float a0 = __shfl(zh0[g], src, 64);
        float a1 = __shfl(zh1[g], src, 64);
        float a2 = __shfl(zh2[g], src, 64);
        hv0 = zs ? a0 : a1; hv1 = zs ? a1 : a2;
      }
      const int dj0 = j0 + jn - iw0 - qr;
#pragma unroll
      for (int f = 0; f < 2; ++f) {
        const int dj = dj0 + (f << 4);
        const float bd = (dj <= 0) ? (f ? lo1 : lo0) : ((dj == 1) ? 0.f : (f ? hv1 : hv0));
        const float acv = f ? ac1[g] : ac0[g];
        float sr = (acv + bd) * SCALEF;
        sr = fminf(fmaxf(sr, -15.f), 15.f);
        const float e2 = __expf(2.f * sr);
        const float scv = 10.f - 20.f * __builtin_amdgcn_rcpf(e2 + 1.f);
        swsr[g][j0 + (f << 4)] = __float2half(scv);
        const float pw = __expf(scv);
        const _Float16 ph = (_Float16)pw;
        ls[g] += (float)ph;
        sm[OFF_P + w * 640 + qr * 40 + (f << 4) + jn] = ph;
      }
    }

    // ---- PV: out += P(f16) . V^T(f16) (P is per-wave private: no barrier) ----
    {
      f16x8 pa = *(const f16x8*)&sm[OFF_P + w * 640 + jn * 40 + colq];
      f16x8 v0 = *(const f16x8*)&sm[OFF_VT + buf + jn * 40 + colq];
      f16x8 v1 = *(const f16x8*)&sm[OFF_VT + buf + (16 + jn) * 40 + colq];
      out0 = MFMAH(pa, v0, out0);
      out1 = MFMAH(pa, v1, out1);
    }
  }

  // ---- epilogue: rowsum reduce + normalized out write ----
#pragma unroll
  for (int g = 0; g < 4; ++g) {
    float s = ls[g];
    s += __shfl_xor(s, 1, 64); s += __shfl_xor(s, 2, 64);
    s += __shfl_xor(s, 4, 64); s += __shfl_xor(s, 8, 64);
    const float inv = 1.0f / s;
    const int qr = (quad << 2) + g;
    float* op = out + (size_t)(iw0 + qr) * 2048 + b * HID + n * DH;
    op[jn] = out0[g] * inv;
    op[16 + jn] = out1[g] * inv;
  }
}

// =================== fast path: probs kernel v4 (1024 threads, 16 waves) ===================
__global__ __launch_bounds__(1024)
void relattn_probs_86028194939537(const __half* __restrict__ sws, const int* __restrict__ mask,
                                  float* __restrict__ probs) {
  __shared__ _Float16 ebuf[8][1032];     // 16.1 KB
  __shared__ unsigned char mb[8192];     // 8 KB
  __shared__ float psum[8][4];
  __shared__ float binv[8];
  const int t = threadIdx.x;
  const int i = blockIdx.x;
  const int tj = t & 255, bg = t >> 8;   // bg in 0..3 -> b = 2bg, 2bg+1
  const int j4 = tj << 2;
  const int wl = (t >> 6) & 3;           // wave-within-b-group

  // stage mask coalesced: 8192 ints -> 8192 bytes
  {
    const int4* m4 = (const int4*)(mask + (size_t)i * 8192);
#pragma unroll
    for (int u = 0; u < 2; ++u) {
      int idx = t + (u << 10);
      int4 mv = m4[idx];
      uchar4 mbv;
      mbv.x = (unsigned char)(mv.x != 0); mbv.y = (unsigned char)(mv.y != 0);
      mbv.z = (unsigned char)(mv.z != 0); mbv.w = (unsigned char)(mv.w != 0);
      *(uchar4*)&mb[idx << 2] = mbv;
    }
  }
  __syncthreads();

#pragma unroll
  for (int bb = 0; bb < 2; ++bb) {
    const int b = (bg << 1) + bb;
    float a0 = 0.f, a1 = 0.f, a2 = 0.f, a3 = 0.f;
#pragma unroll
    for (int n = 0; n < 8; ++n) {
      const __half2* p2 = (const __half2*)(sws + (((size_t)i * 8 + b) * 8 + n) * 1024 + j4);
      float2 x = __half22float2(p2[0]), y = __half22float2(p2[1]);
      a0 += x.x; a1 += x.y; a2 += y.x; a3 += y.y;
    }
    float e0 = mb[(j4 + 0) * 8 + b] ? 0.f : __expf(a0 * 0.125f);
    float e1 = mb[(j4 + 1) * 8 + b] ? 0.f : __expf(a1 * 0.125f);
    float e2 = mb[(j4 + 2) * 8 + b] ? 0.f : __expf(a2 * 0.125f);
    float e3 = mb[(j4 + 3) * 8 + b] ? 0.f : __expf(a3 * 0.125f);
    f16x4 ev;
    ev.x = (_Float16)e0; ev.y = (_Float16)e1; ev.z = (_Float16)e2; ev.w = (_Float16)e3;
    *(f16x4*)&ebuf[b][j4] = ev;
    float s = ((float)ev.x + (float)ev.y) + ((float)ev.z + (float)ev.w);
#pragma unroll
    for (int off = 32; off > 0; off >>= 1) s += __shfl_xor(s, off, 64);
    if ((t & 63) == 0) psum[b][wl] = s;
  }
  __syncthreads();
  if (t < 8) binv[t] = 1.0f / (psum[t][0] + psum[t][1] + psum[t][2] + psum[t][3]);
  __syncthreads();
  // coalesced float4 writes of all 8192 (j,b) values (2 per thread)
#pragma unroll
  for (int u = 0; u < 2; ++u) {
    int f0 = (t << 2) + (u << 12);
    float4 o;
    o.x = (float)ebuf[(f0 + 0) & 7][(f0 + 0) >> 3] * binv[(f0 + 0) & 7];
    o.y = (float)ebuf[(f0 + 1) & 7][(f0 + 1) >> 3] * binv[(f0 + 1) & 7];
    o.z = (float)ebuf[(f0 + 2) & 7][(f0 + 2) >> 3] * binv[(f0 + 2) & 7];
    o.w = (float)ebuf[(f0 + 3) & 7][(f0 + 3) >> 3] * binv[(f0 + 3) & 7];
    *(float4*)(probs + (size_t)i * 8192 + f0) = o;
  }
}

// =================== fallback (R4, proven) ===================
#define TI 8
#define TJ 8
#define NTILE (S / TJ)
#define KSTR 288
#define KOFF 0
#define VOFF (TJ * KSTR)
#define BAND (2 * TJ * KSTR)
#define PROWS (TI + TJ - 1)
#define BSTR 292
#define BVR (BAND + PROWS * BSTR)
#define BUKo (BVR + PROWS * 8)
#define LDS_FL (BUKo + 64)

__global__ __launch_bounds__(256, 2)
void relattn_main_fb(const float* __restrict__ q, const float* __restrict__ k,
                     const float* __restrict__ v, const float* __restrict__ r,
                     const float* __restrict__ bias_u, const float* __restrict__ bias_v,
                     const int* __restrict__ mask, float* __restrict__ out,
                     float* __restrict__ probs_raw, float* __restrict__ ws_logits, int use_ws) {
  __shared__ float smf[LDS_FL];
  const int t = threadIdx.x;
  const int n = t & 7;
  const int il = (t >> 3) & 7;
  const int jp = t >> 6;
  const int bid = blockIdx.x;
  const int b = bid & 7;
  const int i0 = (bid >> 3) * TI;
  const int i = i0 + il;
  float qq[DH], qn[DH];
  {
    const float4* qr = (const float4*)(q + (i * B + b) * HID + n * DH);
#pragma unroll
    for (int dd = 0; dd < 8; ++dd) {
      float4 a = qr[dd];
      qq[4*dd+0] = a.x; qq[4*dd+1] = a.y; qq[4*dd+2] = a.z; qq[4*dd+3] = a.w;
    }
    if (i + 1 < S) {
      const float4* q2 = (const float4*)(q + ((i + 1) * B + b) * HID + n * DH);
#pragma unroll
      for (int dd = 0; dd < 8; ++dd) {
        float4 a = q2[dd];
        qn[4*dd+0] = a.x; qn[4*dd+1] = a.y; qn[4*dd+2] = a.z; qn[4*dd+3] = a.w;
      }
    } else {
#pragma unroll
      for (int d = 0; d < DH; ++d) qn[d] = 0.f;
    }
  }
  float oacc[DH];
#pragma unroll
  for (int d = 0; d < DH; ++d) oacc[d] = 0.f;
  float lsum = 0.f;
  for (int jt = 0; jt < NTILE; ++jt) {
    const int j0 = jt * TJ;
    const int Pstar = i0 + (TI - 1) - j0;
    const int lowBase = S - TI + j0 - i0;
    const int upBase = j0 - i0 - (TI + 1);
    __syncthreads();
    {
      int u = t;
      int row = u >> 6, c = u & 63;
      int gofs = ((j0 + row) * B + b) * HID + c * 4;
      int lofs = row * KSTR + (c >> 3) * 36 + (c & 7) * 4;
      *(float4*)(smf + KOFF + lofs) = *(const float4*)(k + gofs);
      *(float4*)(smf + VOFF + lofs) = *(const float4*)(v + gofs);
      u = t + 256; row = u >> 6; c = u & 63;
      gofs = ((j0 + row) * B + b) * HID + c * 4;
      lofs = row * KSTR + (c >> 3) * 36 + (c & 7) * 4;
      *(float4*)(smf + KOFF + lofs) = *(const float4*)(k + gofs);
      *(float4*)(smf + VOFF + lofs) = *(const float4*)(v + gofs);
    }
    for (int u = t; u < PROWS * 64; u += 256) {
      int prow = u >> 6, c = u & 63;
      int trow = (prow <= Pstar) ? (lowBase + prow) : (upBase + prow);
      float4 val = make_float4(0.f, 0.f, 0.f, 0.f);
      if ((unsigned)trow < (unsigned)S) val = *(const float4*)(r + trow * HID + c * 4);
      *(float4*)(smf + BAND + prow * BSTR + (c >> 3) * 36 + (c & 7) * 4) = val;
    }
    if (t < 64 + PROWS * 8) {
      const float4 *bb, *src;
      int slot;
      bool zero = false;
      if (t < 64) {
        int jl = t >> 3, nn = t & 7;
        bb = (const float4*)(bias_u + nn * DH);
        src = (const float4*)(k + ((j0 + jl) * B + b) * HID + nn * DH);
        slot = BUKo + jl * 8 + nn;
      } else {
        int u2 = t - 64;
        int prow = u2 >> 3, nn = u2 & 7;
        int trow = (prow <= Pstar) ? (lowBase + prow) : (upBase + prow);
        bb = (const float4*)(bias_v + nn * DH);
        if ((unsigned)trow < (unsigned)S) src = (const float4*)(r + trow * HID + nn * DH);
        else { src = bb; zero = true; }
        slot = BVR + prow * 8 + nn;
      }
      float a0 = 0.f, a1 = 0.f, a2 = 0.f, a3 = 0.f;
#pragma unroll
      for (int dd = 0; dd < 8; ++dd) {
        float4 x = bb[dd], y = src[dd];
        a0 = fmaf(x.x, y.x, a0); a1 = fmaf(x.y, y.y, a1);
        a2 = fmaf(x.z, y.z, a2); a3 = fmaf(x.w, y.w, a3);
      }
      smf[slot] = zero ? 0.f : ((a0 + a1) + (a2 + a3));
    }
    __syncthreads();
#pragma unroll
    for (int jj = 0; jj < 2; ++jj) {
      const int jl = jp * 2 + jj;
      const int jg = j0 + jl;
      const int p = jl + (TI - 1) - il;
      float a0 = 0.f, a1 = 0.f, a2 = 0.f, a3 = 0.f;
      const float4* kr = (const float4*)(smf + KOFF + jl * KSTR + n * 36);
#pragma unroll
      for (int dd = 0; dd < 8; ++dd) {
        float4 kv = kr[dd];
        a0 = fmaf(qq[4*dd+0], kv.x, a0); a1 = fmaf(qq[4*dd+1], kv.y, a1);
        a2 = fmaf(qq[4*dd+2], kv.z, a2); a3 = fmaf(qq[4*dd+3], kv.w, a3);
      }
      float ac = (a0 + a1) + (a2 + a3) + smf[BUKo + jl * 8 + n];
      float b0 = 0.f, b1 = 0.f, b2 = 0.f, b3 = 0.f;
      const float4* br = (const float4*)(smf + BAND + p * BSTR + n * 36);
      if (jg <= i) {
#pragma unroll
        for (int dd = 0; dd < 8; ++dd) {
          float4 bv4 = br[dd];
          b0 = fmaf(qq[4*dd+0], bv4.x, b0); b1 = fmaf(qq[4*dd+1], bv4.y, b1);
          b2 = fmaf(qq[4*dd+2], bv4.z, b2); b3 = fmaf(qq[4*dd+3], bv4.w, b3);
        }
      } else {
#pragma unroll
        for (int dd = 0; dd < 8; ++dd) {
          float4 bv4 = br[dd];
          b0 = fmaf(qn[4*dd+0], bv4.x, b0); b1 = fmaf(qn[4*dd+1], bv4.y, b1);
          b2 = fmaf(qn[4*dd+2], bv4.z, b2); b3 = fmaf(qn[4*dd+3], bv4.w, b3);
        }
      }
      float bd = (b0 + b1) + (b2 + b3) + smf[BVR + p * 8 + n];
      float sr = (ac + bd) * SCALEF;
      sr = fminf(fmaxf(sr, -15.f), 15.f);
      float e2 = __expf(2.f * sr);
      float scv = 10.f * (e2 - 1.f) / (e2 + 1.f);
      float ssum = scv;
      ssum += __shfl_xor(ssum, 1, 64);
      ssum += __shfl_xor(ssum, 2, 64);
      ssum += __shfl_xor(ssum, 4, 64);
      if (n == 0) {
        float logit = ssum * 0.125f;
        if (use_ws) {
          ws_logits[(i * B + b) * S + jg] = logit;
        } else {
          int gofs = (i * S + jg) * B + b;
          probs_raw[gofs] = (mask[gofs] != 0) ? -1e30f : logit;
        }
      }
      float pw = __expf(scv);
      lsum += pw;
      const float4* vr = (const float4*)(smf + VOFF + jl * KSTR + n * 36);
#pragma unroll
      for (int dd = 0; dd < 8; ++dd) {
        float4 vv = vr[dd];
        oacc[4*dd+0] = fmaf(pw, vv.x, oacc[4*dd+0]);
        oacc[4*dd+1] = fmaf(pw, vv.y, oacc[4*dd+1]);
        oacc[4*dd+2] = fmaf(pw, vv.z, oacc[4*dd+2]);
        oacc[4*dd+3] = fmaf(pw, vv.w, oacc[4*dd+3]);
      }
    }
  }
  __syncthreads();
  if (jp >= 2) {
    float* red = smf + (t - 128) * 33;
#pragma unroll
    for (int d = 0; d < DH; ++d) red[d] = oacc[d];
    red[DH] = lsum;
  }
  __syncthreads();
  if (jp < 2) {
    const float* red = smf + t * 33;
#pragma unroll
    for (int d = 0; d < DH; ++d) oacc[d] += red[d];
    lsum += red[DH];
  }
  __syncthreads();
  if (jp == 1) {
    float* red = smf + (t - 64) * 33;
#pragma unroll
    for (int d = 0; d < DH; ++d) red[d] = oacc[d];
    red[DH] = lsum;
  }
  __syncthreads();
  if (jp == 0) {
    const float* red = smf + t * 33;
#pragma unroll
    for (int d = 0; d < DH; ++d) oacc[d] += red[d];
    lsum += red[DH];
    float inv = 1.f / lsum;
    float4* orow = (float4*)(out + (i * B + b) * HID + n * DH);
#pragma unroll
    for (int dd = 0; dd < 8; ++dd) {
      float4 o4;
      o4.x = oacc[4*dd+0] * inv; o4.y = oacc[4*dd+1] * inv;
      o4.z = oacc[4*dd+2] * inv; o4.w = oacc[4*dd+3] * inv;
      orow[dd] = o4;
    }
  }
}

__global__ __launch_bounds__(256)
void relattn_norm_fb(float* __restrict__ probs, const float* __restrict__ ws_logits,
                     const int* __restrict__ mask, int use_ws) {
  const int t = threadIdx.x;
  const int bid = blockIdx.x;
  const int b = bid & 7;
  const int i = bid >> 3;
  float vals[4];
  float s = 0.f;
#pragma unroll
  for (int kk = 0; kk < 4; ++kk) {
    int j = t + 256 * kk;
    float lg;
    if (use_ws) {
      lg = ws_logits[(i * B + b) * S + j];
      if (mask[(i * S + j) * B + b] != 0) lg = -1e30f;
    } else {
      lg = probs[(i * S + j) * B + b];
    }
    vals[kk] = __expf(lg);
    s += vals[kk];
  }
#pragma unroll
  for (int off = 32; off > 0; off >>= 1) s += __shfl_down(s, off, 64);
  __shared__ float wsum[4];
  __shared__ float tot;
  if ((t & 63) == 0) wsum[t >> 6] = s;
  __syncthreads();
  if (t == 0) tot = wsum[0] + wsum[1] + wsum[2] + wsum[3];
  __syncthreads();
  float inv = 1.f / tot;
#pragma unroll
  for (int kk = 0; kk < 4; ++kk) {
    int j = t + 256 * kk;
    probs[(i * S + j) * B + b] = vals[kk] * inv;
  }
}

extern "C" void kernel_launch(void* const* d_in, const int* in_sizes, int n_in,
                              void* d_out, int out_size, void* d_ws, size_t ws_size,
                              hipStream_t stream) {
  const float* q  = (const float*)d_in[0];
  const float* k  = (const float*)d_in[1];
  const float* v  = (const float*)d_in[2];
  const float* r  = (const float*)d_in[3];
  const float* bu = (const float*)d_in[4];
  const float* bv = (const float*)d_in[5];
  const int* mask = (const int*)d_in[6];
  float* out = (float*)d_out;
  float* probs = out + S * B * HID;

  const size_t WS_NEED = (size_t)S * S * B * NH * sizeof(__half);  // 128 MiB
  if (ws_size >= WS_NEED) {
    __half* sws = (__half*)d_ws;
    relattn_mfma_86028194939537<<<dim3(1024), dim3(256), 0, stream>>>(
        q, k, v, r, bu, bv, out, sws);
    relattn_probs_86028194939537<<<dim3(1024), dim3(1024), 0, stream>>>(sws, mask, probs);
  } else {
    float* wsl = (float*)d_ws;
    const int use_ws = (ws_size >= (size_t)S * S * B * sizeof(float)) ? 1 : 0;
    relattn_main_fb<<<dim3((S / TI) * B), dim3(256), 0, stream>>>(
        q, k, v, r, bu, bv, mask, out, probs, wsl, use_ws);
    relattn_norm_fb<<<dim3(S * B), dim3(256), 0, stream>>>(probs, wsl, mask, use_ws);
  }
}